// Round 1
// baseline (549.562 us; speedup 1.0000x reference)
//
#include <hip/hip_runtime.h>
#include <hip/hip_bf16.h>

// out[r, n] = relu( sum_k concat[r,k] * W[k,n] ),
// concat = [review_row | user_row[perm_u] | item_row[perm_i]]
// WT has W's rows pre-permuted (prep_WT) so gathers are contiguous rows.
//
// v2: persistent blocks (768 = 3/CU), grid-stride over 64-row tiles.
//     - WT staged to LDS once per block (was: once per tile = 375 MB L2 traffic)
//     - register prefetch pipeline: gathers for tile t+1 issued before compute
//       of tile t; adjacency prefetched 2 tiles ahead (breaks the adj->gather
//       dependent-latency chain)
//     - ZERO barriers in the loop: wave wv stages AND computes rows
//       [16wv,16wv+16) of ldsX -- no cross-wave sharing of X; only the
//       read-only ldsW needs the single post-stage __syncthreads.

#define DIMS 64
#define K3 192
#define MTILE 64
#define LDST 208       // LDS row stride in bf16 units (192 + 16 pad)
#define NPERSIST 768   // 3 blocks/CU * 256 CUs (LDS-limited occupancy)

typedef float f32x4 __attribute__((ext_vector_type(4)));
typedef short s16x8 __attribute__((ext_vector_type(8)));
typedef __bf16 bf16x8 __attribute__((ext_vector_type(8)));

__device__ __forceinline__ short f2bf(float f) {
    union { float f; unsigned int u; } v; v.f = f;
    unsigned int u = v.u;
    u += 0x7fffu + ((u >> 16) & 1u);   // round-to-nearest-even
    return (short)(u >> 16);
}

// Prep: WT[n*192 + dk] = bf16(W[k*64+n]) with dk the permuted destination k.
__global__ void prep_WT(const float* __restrict__ W,
                        const int* __restrict__ perm_u,
                        const int* __restrict__ perm_i,
                        short* __restrict__ WT) {
    const int t = threadIdx.x;
    #pragma unroll 4
    for (int i = 0; i < 48; ++i) {
        int e = t + i * 256;          // 0..12287
        int k = e >> 6;               // 0..191
        int n = e & 63;
        float w = W[e];               // coalesced: W[k*64+n]
        int dk;
        if (k < 64)       dk = k;
        else if (k < 128) dk = 64 + perm_u[k - 64];
        else              dk = 128 + perm_i[k - 128];
        WT[n * K3 + dk] = f2bf(w);
    }
}

__device__ __forceinline__ void load16(const float* __restrict__ src, float4* v) {
    const float4* s4 = (const float4*)src;
    v[0] = s4[0]; v[1] = s4[1]; v[2] = s4[2]; v[3] = s4[3];
}

__device__ __forceinline__ void pack16(const float4* v, short* dst) {
    s16x8 lo, hi;
    lo[0] = f2bf(v[0].x); lo[1] = f2bf(v[0].y); lo[2] = f2bf(v[0].z); lo[3] = f2bf(v[0].w);
    lo[4] = f2bf(v[1].x); lo[5] = f2bf(v[1].y); lo[6] = f2bf(v[1].z); lo[7] = f2bf(v[1].w);
    hi[0] = f2bf(v[2].x); hi[1] = f2bf(v[2].y); hi[2] = f2bf(v[2].z); hi[3] = f2bf(v[2].w);
    hi[4] = f2bf(v[3].x); hi[5] = f2bf(v[3].y); hi[6] = f2bf(v[3].z); hi[7] = f2bf(v[3].w);
    ((s16x8*)dst)[0] = lo;
    ((s16x8*)dst)[1] = hi;
}

__global__ __launch_bounds__(256, 3) void concat_agg_kernel(
        const float* __restrict__ review,
        const float* __restrict__ user,
        const float* __restrict__ item,
        const int* __restrict__ uadj,
        const int* __restrict__ iadj,
        const short* __restrict__ WT,    // bf16 bits, [64][192] packed
        float* __restrict__ out,
        int n_reviews, int ntiles) {
    __shared__ short ldsX[MTILE * LDST];  // 26624 B
    __shared__ short ldsW[DIMS * LDST];   // 26624 B

    const int t = threadIdx.x;
    int tile = blockIdx.x;
    if (tile >= ntiles) return;

    // --- stage WT once per block (1536 chunks of 8 bf16; 6 per thread) ---
    #pragma unroll
    for (int i = 0; i < 6; ++i) {
        int c = t + i * 256;
        int n = c / 24;
        int k = (c - n * 24) * 8;
        *(s16x8*)&ldsW[n * LDST + k] = *(const s16x8*)(WT + c * 8);
    }

    const int rloc = t >> 2;          // 4 threads per row
    const int seg  = (t & 3) * 16;
    const int lane = t & 63;
    const int wv   = t >> 6;          // 0..3
    const int m    = lane & 15;
    const int q    = lane >> 4;       // 0..3
    const int nstep = gridDim.x;

    short* xrow = &ldsX[rloc * LDST];                       // own staging row
    const short* xa  = &ldsX[(wv * 16 + m) * LDST + q * 8]; // own wave's slice
    const short* wb0 = &ldsW[m * LDST + q * 8];

    // --- prologue: load first tile's data into regs ---
    float4 qr[12];
    {
        int row = tile * MTILE + rloc;
        if (row >= n_reviews) row = n_reviews - 1;
        int u_c = uadj[row];
        int i_c = iadj[row];
        load16(review + (size_t)row * DIMS + seg, &qr[0]);
        load16(user   + (size_t)u_c * DIMS + seg, &qr[4]);
        load16(item   + (size_t)i_c * DIMS + seg, &qr[8]);
    }
    // adjacency prefetch for the NEXT tile (2-deep pipeline on adj)
    int u_n, i_n;
    {
        int tn = tile + nstep;
        int prow = tile * MTILE + rloc;
        if (tn < ntiles) prow = tn * MTILE + rloc;
        if (prow >= n_reviews) prow = n_reviews - 1;
        u_n = uadj[prow];
        i_n = iadj[prow];
    }
    pack16(&qr[0], xrow + seg);
    pack16(&qr[4], xrow + 64 + seg);
    pack16(&qr[8], xrow + 128 + seg);

    __syncthreads();   // ldsW ready; the ONLY barrier in the kernel

    for (;;) {
        const int tnext = tile + nstep;
        const bool has_next = (tnext < ntiles);   // uniform across block

        // --- issue gathers for tile t+1 BEFORE computing tile t ---
        int u_nn = u_n, i_nn = i_n;
        if (has_next) {
            int nr = tnext * MTILE + rloc;
            if (nr >= n_reviews) nr = n_reviews - 1;
            load16(review + (size_t)nr * DIMS + seg, &qr[0]);
            load16(user   + (size_t)u_n * DIMS + seg, &qr[4]);
            load16(item   + (size_t)i_n * DIMS + seg, &qr[8]);
            int tnn = tnext + nstep;
            int nnr = nr;
            if (tnn < ntiles) {
                nnr = tnn * MTILE + rloc;
                if (nnr >= n_reviews) nnr = n_reviews - 1;
            }
            u_nn = uadj[nnr];
            i_nn = iadj[nnr];
        }

        // --- MFMA on current tile (wave reads only its own 16 rows) ---
        f32x4 acc0 = {0.f,0.f,0.f,0.f}, acc1 = {0.f,0.f,0.f,0.f};
        f32x4 acc2 = {0.f,0.f,0.f,0.f}, acc3 = {0.f,0.f,0.f,0.f};
        #pragma unroll
        for (int ks = 0; ks < 6; ++ks) {
            bf16x8 a  = __builtin_bit_cast(bf16x8, *(const s16x8*)(xa + ks * 32));
            bf16x8 b0 = __builtin_bit_cast(bf16x8, *(const s16x8*)(wb0 + 0 * 16 * LDST + ks * 32));
            bf16x8 b1 = __builtin_bit_cast(bf16x8, *(const s16x8*)(wb0 + 1 * 16 * LDST + ks * 32));
            bf16x8 b2 = __builtin_bit_cast(bf16x8, *(const s16x8*)(wb0 + 2 * 16 * LDST + ks * 32));
            bf16x8 b3 = __builtin_bit_cast(bf16x8, *(const s16x8*)(wb0 + 3 * 16 * LDST + ks * 32));
            acc0 = __builtin_amdgcn_mfma_f32_16x16x32_bf16(a, b0, acc0, 0, 0, 0);
            acc1 = __builtin_amdgcn_mfma_f32_16x16x32_bf16(a, b1, acc1, 0, 0, 0);
            acc2 = __builtin_amdgcn_mfma_f32_16x16x32_bf16(a, b2, acc2, 0, 0, 0);
            acc3 = __builtin_amdgcn_mfma_f32_16x16x32_bf16(a, b3, acc3, 0, 0, 0);
        }

        // --- epilogue: C/D layout col = lane&15, row = q*4 + reg ---
        const int r0 = tile * MTILE;
        #pragma unroll
        for (int v = 0; v < 4; ++v) {
            const int rr = r0 + wv * 16 + q * 4 + v;
            if (rr < n_reviews) {
                float* orow = out + (size_t)rr * DIMS + m;
                orow[ 0] = fmaxf(acc0[v], 0.0f);
                orow[16] = fmaxf(acc1[v], 0.0f);
                orow[32] = fmaxf(acc2[v], 0.0f);
                orow[48] = fmaxf(acc3[v], 0.0f);
            }
        }

        if (!has_next) break;

        // --- stage prefetched tile into own LDS slice (vmcnt wait here) ---
        pack16(&qr[0], xrow + seg);
        pack16(&qr[4], xrow + 64 + seg);
        pack16(&qr[8], xrow + 128 + seg);
        u_n = u_nn; i_n = i_nn;
        tile = tnext;
    }
}

extern "C" void kernel_launch(void* const* d_in, const int* in_sizes, int n_in,
                              void* d_out, int out_size, void* d_ws, size_t ws_size,
                              hipStream_t stream) {
    (void)n_in; (void)out_size; (void)ws_size;
    const float* review = (const float*)d_in[0];
    const float* user   = (const float*)d_in[1];
    const float* item   = (const float*)d_in[2];
    const float* W      = (const float*)d_in[3];
    const int* uadj     = (const int*)d_in[4];
    const int* iadj     = (const int*)d_in[5];
    const int* perm_u   = (const int*)d_in[6];
    const int* perm_i   = (const int*)d_in[7];
    float* out = (float*)d_out;
    short* WT = (short*)d_ws;  // 12288 bf16 = 24 KB scratch

    const int n_reviews = in_sizes[0] / DIMS;
    const int ntiles = (n_reviews + MTILE - 1) / MTILE;

    prep_WT<<<1, 256, 0, stream>>>(W, perm_u, perm_i, WT);

    const int grid = ntiles < NPERSIST ? ntiles : NPERSIST;
    concat_agg_kernel<<<grid, 256, 0, stream>>>(review, user, item, uadj, iadj,
                                                WT, out, n_reviews, ntiles);
}

// Round 2
// 527.117 us; speedup vs baseline: 1.0426x; 1.0426x over previous
//
#include <hip/hip_runtime.h>
#include <hip/hip_bf16.h>

// out[r, n] = relu( sum_k concat[r,k] * W[k,n] ),
// concat = [review_row | user_row[perm_u] | item_row[perm_i]]
// WT has W's rows pre-permuted (prep_WT) so gathers are contiguous rows.
//
// v3: kill ldsX entirely. Each lane loads its MFMA A-fragment DIRECTLY from
//     global in fragment order: lane(m,q) of wave wv needs, for ks=0..5,
//     concat[row=16wv+m][32ks + q*8 .. +8] =
//       ks=0,1 -> review[row][q*8], review[row][32+q*8]
//       ks=2,3 -> user [u ] [q*8], user [u ] [32+q*8]
//       ks=4,5 -> item [it] [q*8], item [it] [32+q*8]
//     Same 12 float4 loads per thread as the old LDS stager, but:
//       - no ldsX (LDS 53KB -> 26.6KB: blocks/CU 3 -> 5-6, occupancy ~2x)
//       - no pack16/ds_write/ds_read round-trip for X
//       - adj + gather loads issue BEFORE the WT barrier (latency hidden)
//     Grid back to exact one-tile-per-block (v1 mapping): the v2 persistent
//     grid-stride cost +169MB of L2-miss traffic.

#define DIMS 64
#define K3 192
#define MTILE 64
#define LDST 208       // LDS row stride in bf16 units (192 + 16 pad)

typedef float f32x4 __attribute__((ext_vector_type(4)));
typedef short s16x8 __attribute__((ext_vector_type(8)));
typedef __bf16 bf16x8 __attribute__((ext_vector_type(8)));

__device__ __forceinline__ short f2bf(float f) {
    union { float f; unsigned int u; } v; v.f = f;
    unsigned int u = v.u;
    u += 0x7fffu + ((u >> 16) & 1u);   // round-to-nearest-even
    return (short)(u >> 16);
}

// Prep: WT[n*192 + dk] = bf16(W[k*64+n]) with dk the permuted destination k.
__global__ void prep_WT(const float* __restrict__ W,
                        const int* __restrict__ perm_u,
                        const int* __restrict__ perm_i,
                        short* __restrict__ WT) {
    const int t = threadIdx.x;
    #pragma unroll 4
    for (int i = 0; i < 48; ++i) {
        int e = t + i * 256;          // 0..12287
        int k = e >> 6;               // 0..191
        int n = e & 63;
        float w = W[e];               // coalesced: W[k*64+n]
        int dk;
        if (k < 64)       dk = k;
        else if (k < 128) dk = 64 + perm_u[k - 64];
        else              dk = 128 + perm_i[k - 128];
        WT[n * K3 + dk] = f2bf(w);
    }
}

__device__ __forceinline__ bf16x8 pack8(float4 a, float4 b) {
    s16x8 r;
    r[0] = f2bf(a.x); r[1] = f2bf(a.y); r[2] = f2bf(a.z); r[3] = f2bf(a.w);
    r[4] = f2bf(b.x); r[5] = f2bf(b.y); r[6] = f2bf(b.z); r[7] = f2bf(b.w);
    return __builtin_bit_cast(bf16x8, r);
}

__global__ __launch_bounds__(256, 5) void concat_agg_kernel(
        const float* __restrict__ review,
        const float* __restrict__ user,
        const float* __restrict__ item,
        const int* __restrict__ uadj,
        const int* __restrict__ iadj,
        const short* __restrict__ WT,    // bf16 bits, [64][192] packed
        float* __restrict__ out,
        int n_reviews) {
    __shared__ short ldsW[DIMS * LDST];   // 26624 B (only LDS in the kernel)

    const int t    = threadIdx.x;
    const int lane = t & 63;
    const int wv   = t >> 6;          // 0..3
    const int m    = lane & 15;
    const int q    = lane >> 4;       // 0..3
    const int r0   = blockIdx.x * MTILE;

    int row = r0 + wv * 16 + m;       // per-lane A-fragment row
    if (row >= n_reviews) row = n_reviews - 1;

    // --- adjacency first: its latency hides under WT staging ---
    const int u  = uadj[row];
    const int it = iadj[row];

    // --- stage WT once per block (1536 chunks of 8 bf16; 6 per thread) ---
    #pragma unroll
    for (int i = 0; i < 6; ++i) {
        int c = t + i * 256;
        int n = c / 24;
        int k = (c - n * 24) * 8;
        *(s16x8*)&ldsW[n * LDST + k] = *(const s16x8*)(WT + c * 8);
    }

    // --- issue all 12 X loads in fragment layout (to registers, pre-barrier) ---
    const float* rv = review + (size_t)row * DIMS + q * 8;
    const float* uv = user   + (size_t)u   * DIMS + q * 8;
    const float* iv = item   + (size_t)it  * DIMS + q * 8;
    float4 x0 = ((const float4*)rv)[0],        x1 = ((const float4*)rv)[1];
    float4 x2 = ((const float4*)(rv + 32))[0], x3 = ((const float4*)(rv + 32))[1];
    float4 x4 = ((const float4*)uv)[0],        x5 = ((const float4*)uv)[1];
    float4 x6 = ((const float4*)(uv + 32))[0], x7 = ((const float4*)(uv + 32))[1];
    float4 x8 = ((const float4*)iv)[0],        x9 = ((const float4*)iv)[1];
    float4 xa = ((const float4*)(iv + 32))[0], xb = ((const float4*)(iv + 32))[1];

    __syncthreads();   // ldsW ready (the only barrier)

    // --- convert to A fragments in-register ---
    bf16x8 a0 = pack8(x0, x1);
    bf16x8 a1 = pack8(x2, x3);
    bf16x8 a2 = pack8(x4, x5);
    bf16x8 a3 = pack8(x6, x7);
    bf16x8 a4 = pack8(x8, x9);
    bf16x8 a5 = pack8(xa, xb);
    bf16x8 afr[6] = {a0, a1, a2, a3, a4, a5};  // fully unrolled below -> static idx

    const short* wb0 = &ldsW[m * LDST + q * 8];

    f32x4 acc0 = {0.f,0.f,0.f,0.f}, acc1 = {0.f,0.f,0.f,0.f};
    f32x4 acc2 = {0.f,0.f,0.f,0.f}, acc3 = {0.f,0.f,0.f,0.f};

    #pragma unroll
    for (int ks = 0; ks < 6; ++ks) {
        bf16x8 b0 = __builtin_bit_cast(bf16x8, *(const s16x8*)(wb0 + 0 * 16 * LDST + ks * 32));
        bf16x8 b1 = __builtin_bit_cast(bf16x8, *(const s16x8*)(wb0 + 1 * 16 * LDST + ks * 32));
        bf16x8 b2 = __builtin_bit_cast(bf16x8, *(const s16x8*)(wb0 + 2 * 16 * LDST + ks * 32));
        bf16x8 b3 = __builtin_bit_cast(bf16x8, *(const s16x8*)(wb0 + 3 * 16 * LDST + ks * 32));
        acc0 = __builtin_amdgcn_mfma_f32_16x16x32_bf16(afr[ks], b0, acc0, 0, 0, 0);
        acc1 = __builtin_amdgcn_mfma_f32_16x16x32_bf16(afr[ks], b1, acc1, 0, 0, 0);
        acc2 = __builtin_amdgcn_mfma_f32_16x16x32_bf16(afr[ks], b2, acc2, 0, 0, 0);
        acc3 = __builtin_amdgcn_mfma_f32_16x16x32_bf16(afr[ks], b3, acc3, 0, 0, 0);
    }

    // --- epilogue: C/D layout col = lane&15, row = q*4 + reg ---
    #pragma unroll
    for (int v = 0; v < 4; ++v) {
        const int rr = r0 + wv * 16 + q * 4 + v;
        if (rr < n_reviews) {
            float* orow = out + (size_t)rr * DIMS + m;
            orow[ 0] = fmaxf(acc0[v], 0.0f);
            orow[16] = fmaxf(acc1[v], 0.0f);
            orow[32] = fmaxf(acc2[v], 0.0f);
            orow[48] = fmaxf(acc3[v], 0.0f);
        }
    }
}

extern "C" void kernel_launch(void* const* d_in, const int* in_sizes, int n_in,
                              void* d_out, int out_size, void* d_ws, size_t ws_size,
                              hipStream_t stream) {
    (void)n_in; (void)out_size; (void)ws_size;
    const float* review = (const float*)d_in[0];
    const float* user   = (const float*)d_in[1];
    const float* item   = (const float*)d_in[2];
    const float* W      = (const float*)d_in[3];
    const int* uadj     = (const int*)d_in[4];
    const int* iadj     = (const int*)d_in[5];
    const int* perm_u   = (const int*)d_in[6];
    const int* perm_i   = (const int*)d_in[7];
    float* out = (float*)d_out;
    short* WT = (short*)d_ws;  // 12288 bf16 = 24 KB scratch

    const int n_reviews = in_sizes[0] / DIMS;

    prep_WT<<<1, 256, 0, stream>>>(W, perm_u, perm_i, WT);

    const int grid = (n_reviews + MTILE - 1) / MTILE;
    concat_agg_kernel<<<grid, 256, 0, stream>>>(review, user, item, uadj, iadj,
                                                WT, out, n_reviews);
}

// Round 3
// 509.520 us; speedup vs baseline: 1.0786x; 1.0345x over previous
//
#include <hip/hip_runtime.h>
#include <hip/hip_bf16.h>

// out[r, n] = relu( sum_k concat[r,k] * W[k,n] ),
// concat = [review_row | user_row[perm_u] | item_row[perm_i]]
// WT has W's rows pre-permuted (prep_WT) so gathers are contiguous rows.
//
// v4:
//  - user/item tables pre-converted to bf16 in workspace (prep_tables):
//    gather traffic halves (512->256MB through L2/L3), tables 19.2MB are
//    more L2/L3-resident, gathers land directly as MFMA A-fragments (s16x8),
//    no f2bf VALU on the gather path.
//  - X loads moved AFTER the ldsW barrier: v3 put them before it, and the
//    compiler-mandated s_waitcnt vmcnt(0) at s_barrier let the register
//    allocator serialize them (VGPR_Count=40 -> MLP ~3). After the barrier
//    there is no forced drain; loads issue back-to-back and MFMA on review
//    fragments overlaps in-flight user/item gathers.
//  - __launch_bounds__(256,6): 84-VGPR budget, 6 blocks/CU at 26.6KB LDS.
//  - exact one-tile-per-block grid (v2's persistent stride cost +169MB L2-miss).

#define DIMS 64
#define K3 192
#define MTILE 64
#define LDST 208       // LDS row stride in bf16 units (192 + 16 pad)

typedef float f32x4 __attribute__((ext_vector_type(4)));
typedef short s16x8 __attribute__((ext_vector_type(8)));
typedef __bf16 bf16x8 __attribute__((ext_vector_type(8)));

__device__ __forceinline__ short f2bf(float f) {
    union { float f; unsigned int u; } v; v.f = f;
    unsigned int u = v.u;
    u += 0x7fffu + ((u >> 16) & 1u);   // round-to-nearest-even
    return (short)(u >> 16);
}

// Prep: WT[n*192 + dk] = bf16(W[k*64+n]) with dk the permuted destination k.
__global__ void prep_WT(const float* __restrict__ W,
                        const int* __restrict__ perm_u,
                        const int* __restrict__ perm_i,
                        short* __restrict__ WT) {
    const int t = threadIdx.x;
    #pragma unroll 4
    for (int i = 0; i < 48; ++i) {
        int e = t + i * 256;          // 0..12287
        int k = e >> 6;               // 0..191
        int n = e & 63;
        float w = W[e];               // coalesced: W[k*64+n]
        int dk;
        if (k < 64)       dk = k;
        else if (k < 128) dk = 64 + perm_u[k - 64];
        else              dk = 128 + perm_i[k - 128];
        WT[n * K3 + dk] = f2bf(w);
    }
}

// Convert user+item tables f32 -> bf16 (row layout unchanged).
__global__ void prep_tables(const float* __restrict__ user,
                            const float* __restrict__ item,
                            short* __restrict__ ub, short* __restrict__ ib,
                            int nu, int ni) {   // element counts, multiples of 8
    int i8 = (blockIdx.x * 256 + threadIdx.x) * 8;
    const float* src;
    short* dst;
    if (i8 < nu) {
        src = user + i8; dst = ub + i8;
    } else {
        int j = i8 - nu;
        if (j >= ni) return;
        src = item + j; dst = ib + j;
    }
    float4 a = ((const float4*)src)[0];
    float4 b = ((const float4*)src)[1];
    s16x8 r;
    r[0] = f2bf(a.x); r[1] = f2bf(a.y); r[2] = f2bf(a.z); r[3] = f2bf(a.w);
    r[4] = f2bf(b.x); r[5] = f2bf(b.y); r[6] = f2bf(b.z); r[7] = f2bf(b.w);
    *(s16x8*)dst = r;
}

__device__ __forceinline__ bf16x8 pack8(float4 a, float4 b) {
    s16x8 r;
    r[0] = f2bf(a.x); r[1] = f2bf(a.y); r[2] = f2bf(a.z); r[3] = f2bf(a.w);
    r[4] = f2bf(b.x); r[5] = f2bf(b.y); r[6] = f2bf(b.z); r[7] = f2bf(b.w);
    return __builtin_bit_cast(bf16x8, r);
}

template<int TAB>
__global__ __launch_bounds__(256, 6) void concat_agg_kernel(
        const float* __restrict__ review,
        const float* __restrict__ user,
        const float* __restrict__ item,
        const short* __restrict__ ub,    // bf16 user table (TAB=1)
        const short* __restrict__ ib,    // bf16 item table (TAB=1)
        const int* __restrict__ uadj,
        const int* __restrict__ iadj,
        const short* __restrict__ WT,    // bf16 bits, [64][192] packed
        float* __restrict__ out,
        int n_reviews) {
    __shared__ short ldsW[DIMS * LDST];   // 26624 B (only LDS in the kernel)

    const int t    = threadIdx.x;
    const int lane = t & 63;
    const int wv   = t >> 6;          // 0..3
    const int m    = lane & 15;
    const int q    = lane >> 4;       // 0..3
    const int r0   = blockIdx.x * MTILE;

    int row = r0 + wv * 16 + m;       // per-lane A-fragment row
    if (row >= n_reviews) row = n_reviews - 1;

    // adjacency first: latency hides under WT staging + barrier
    const int u  = uadj[row];
    const int it = iadj[row];

    // --- stage WT once per block (1536 chunks of 8 bf16; 6 per thread) ---
    #pragma unroll
    for (int i = 0; i < 6; ++i) {
        int c = t + i * 256;
        int n = c / 24;
        int k = (c - n * 24) * 8;
        *(s16x8*)&ldsW[n * LDST + k] = *(const s16x8*)(WT + c * 8);
    }

    __syncthreads();   // ldsW ready; X loads issue AFTER this (no vmcnt(0) drain)

    // --- X loads in fragment layout, consumption order: review, user, item ---
    const float* rv = review + (size_t)row * DIMS + q * 8;
    float4 x0 = ((const float4*)rv)[0];
    float4 x1 = ((const float4*)rv)[1];
    float4 x2 = ((const float4*)(rv + 32))[0];
    float4 x3 = ((const float4*)(rv + 32))[1];

    bf16x8 a2, a3, a4, a5;
    if (TAB) {
        const short* uvp = ub + (size_t)u  * DIMS + q * 8;
        const short* ivp = ib + (size_t)it * DIMS + q * 8;
        a2 = __builtin_bit_cast(bf16x8, *(const s16x8*)uvp);
        a3 = __builtin_bit_cast(bf16x8, *(const s16x8*)(uvp + 32));
        a4 = __builtin_bit_cast(bf16x8, *(const s16x8*)ivp);
        a5 = __builtin_bit_cast(bf16x8, *(const s16x8*)(ivp + 32));
    } else {
        const float* uv = user + (size_t)u  * DIMS + q * 8;
        const float* iv = item + (size_t)it * DIMS + q * 8;
        float4 u0 = ((const float4*)uv)[0],        u1 = ((const float4*)uv)[1];
        float4 u2 = ((const float4*)(uv + 32))[0], u3 = ((const float4*)(uv + 32))[1];
        float4 i0 = ((const float4*)iv)[0],        i1 = ((const float4*)iv)[1];
        float4 i2 = ((const float4*)(iv + 32))[0], i3 = ((const float4*)(iv + 32))[1];
        a2 = pack8(u0, u1); a3 = pack8(u2, u3);
        a4 = pack8(i0, i1); a5 = pack8(i2, i3);
    }
    bf16x8 a0 = pack8(x0, x1);
    bf16x8 a1 = pack8(x2, x3);

    const short* wb0 = &ldsW[m * LDST + q * 8];

    f32x4 acc0 = {0.f,0.f,0.f,0.f}, acc1 = {0.f,0.f,0.f,0.f};
    f32x4 acc2 = {0.f,0.f,0.f,0.f}, acc3 = {0.f,0.f,0.f,0.f};

    #define KSTEP(A, KS) do { \
        bf16x8 b0 = __builtin_bit_cast(bf16x8, *(const s16x8*)(wb0 + 0 * 16 * LDST + (KS) * 32)); \
        bf16x8 b1 = __builtin_bit_cast(bf16x8, *(const s16x8*)(wb0 + 1 * 16 * LDST + (KS) * 32)); \
        bf16x8 b2 = __builtin_bit_cast(bf16x8, *(const s16x8*)(wb0 + 2 * 16 * LDST + (KS) * 32)); \
        bf16x8 b3 = __builtin_bit_cast(bf16x8, *(const s16x8*)(wb0 + 3 * 16 * LDST + (KS) * 32)); \
        acc0 = __builtin_amdgcn_mfma_f32_16x16x32_bf16((A), b0, acc0, 0, 0, 0); \
        acc1 = __builtin_amdgcn_mfma_f32_16x16x32_bf16((A), b1, acc1, 0, 0, 0); \
        acc2 = __builtin_amdgcn_mfma_f32_16x16x32_bf16((A), b2, acc2, 0, 0, 0); \
        acc3 = __builtin_amdgcn_mfma_f32_16x16x32_bf16((A), b3, acc3, 0, 0, 0); \
    } while (0)

    KSTEP(a0, 0);
    KSTEP(a1, 1);
    KSTEP(a2, 2);
    KSTEP(a3, 3);
    KSTEP(a4, 4);
    KSTEP(a5, 5);
    #undef KSTEP

    // --- epilogue: C/D layout col = lane&15, row = q*4 + reg ---
    #pragma unroll
    for (int v = 0; v < 4; ++v) {
        const int rr = r0 + wv * 16 + q * 4 + v;
        if (rr < n_reviews) {
            float* orow = out + (size_t)rr * DIMS + m;
            orow[ 0] = fmaxf(acc0[v], 0.0f);
            orow[16] = fmaxf(acc1[v], 0.0f);
            orow[32] = fmaxf(acc2[v], 0.0f);
            orow[48] = fmaxf(acc3[v], 0.0f);
        }
    }
}

extern "C" void kernel_launch(void* const* d_in, const int* in_sizes, int n_in,
                              void* d_out, int out_size, void* d_ws, size_t ws_size,
                              hipStream_t stream) {
    (void)n_in; (void)out_size;
    const float* review = (const float*)d_in[0];
    const float* user   = (const float*)d_in[1];
    const float* item   = (const float*)d_in[2];
    const float* W      = (const float*)d_in[3];
    const int* uadj     = (const int*)d_in[4];
    const int* iadj     = (const int*)d_in[5];
    const int* perm_u   = (const int*)d_in[6];
    const int* perm_i   = (const int*)d_in[7];
    float* out = (float*)d_out;

    const int n_reviews = in_sizes[0] / DIMS;
    const int nu = in_sizes[1];    // user table float count (100000*64)
    const int ni = in_sizes[2];    // item table float count (50000*64)

    short* WT = (short*)d_ws;      // 24576 B at offset 0
    const size_t off_ub = 32768;
    const size_t need = off_ub + (size_t)(nu + ni) * sizeof(short);

    prep_WT<<<1, 256, 0, stream>>>(W, perm_u, perm_i, WT);

    const int grid = (n_reviews + MTILE - 1) / MTILE;

    if (ws_size >= need) {
        short* UB = (short*)((char*)d_ws + off_ub);
        short* IB = UB + nu;
        const int tot8 = (nu + ni) / 8;
        prep_tables<<<(tot8 + 255) / 256, 256, 0, stream>>>(user, item, UB, IB, nu, ni);
        concat_agg_kernel<1><<<grid, 256, 0, stream>>>(review, user, item, UB, IB,
                                                       uadj, iadj, WT, out, n_reviews);
    } else {
        concat_agg_kernel<0><<<grid, 256, 0, stream>>>(review, user, item, nullptr, nullptr,
                                                       uadj, iadj, WT, out, n_reviews);
    }
}

// Round 4
// 483.296 us; speedup vs baseline: 1.1371x; 1.0543x over previous
//
#include <hip/hip_runtime.h>
#include <hip/hip_bf16.h>

// out[r, n] = relu( sum_k concat[r,k] * W[k,n] ),
// concat = [review_row | user_row[perm_u] | item_row[perm_i]]
// WT has W's rows pre-permuted so gathers are contiguous rows.
//
// v5 (on top of v4):
//  - prep_WT + prep_tables merged into ONE kernel (prep_all): WT built by 6
//    parallel blocks (was 1 block, ~8-10us serial) running concurrently with
//    the table f32->bf16 conversion. One launch instead of two.
//  - pack8 uses native float->__bf16 casts: gfx950 lowers fptrunc to
//    v_cvt_pk_bf16_f32 (1 VALU per pair vs ~6 for the hand-rolled RNE).
//    Numerics identical (both round-to-nearest-even).
//  - main kernel unchanged from v4: bf16 tables gathered directly as MFMA
//    A-fragments after the ldsW barrier, 26.6KB LDS, 6 blocks/CU.

#define DIMS 64
#define K3 192
#define MTILE 64
#define LDST 208       // LDS row stride in bf16 units (192 + 16 pad)

typedef float f32x4 __attribute__((ext_vector_type(4)));
typedef short s16x8 __attribute__((ext_vector_type(8)));
typedef __bf16 bf16x8 __attribute__((ext_vector_type(8)));

__device__ __forceinline__ short f2bf(float f) {
    union { float f; unsigned int u; } v; v.f = f;
    unsigned int u = v.u;
    u += 0x7fffu + ((u >> 16) & 1u);   // round-to-nearest-even
    return (short)(u >> 16);
}

__device__ __forceinline__ void wt_part(const float* __restrict__ W,
                                        const int* __restrict__ perm_u,
                                        const int* __restrict__ perm_i,
                                        short* __restrict__ WT,
                                        int wtb, int t) {
    #pragma unroll
    for (int i = 0; i < 8; ++i) {
        int e = t + (wtb * 8 + i) * 256;  // 0..12287 over 6 blocks
        int k = e >> 6;                   // 0..191
        int n = e & 63;
        float w = W[e];                   // coalesced
        int dk;
        if (k < 64)       dk = k;
        else if (k < 128) dk = 64 + perm_u[k - 64];
        else              dk = 128 + perm_i[k - 128];
        WT[n * K3 + dk] = f2bf(w);
    }
}

// Fallback (small workspace): WT only, 6 blocks.
__global__ void prep_WT(const float* __restrict__ W,
                        const int* __restrict__ perm_u,
                        const int* __restrict__ perm_i,
                        short* __restrict__ WT) {
    wt_part(W, perm_u, perm_i, WT, blockIdx.x, threadIdx.x);
}

// Merged prep: blocks [0, tabBlocks) convert user+item tables f32->bf16;
// blocks [tabBlocks, tabBlocks+6) build WT. One launch, fully parallel.
__global__ void prep_all(const float* __restrict__ W,
                         const int* __restrict__ perm_u,
                         const int* __restrict__ perm_i,
                         const float* __restrict__ user,
                         const float* __restrict__ item,
                         short* __restrict__ WT,
                         short* __restrict__ ub, short* __restrict__ ib,
                         int nu, int ni, int tabBlocks) {
    const int t = threadIdx.x;
    const int b = blockIdx.x;
    if (b >= tabBlocks) {
        wt_part(W, perm_u, perm_i, WT, b - tabBlocks, t);
        return;
    }
    int i8 = (b * 256 + t) * 8;
    const float* src;
    short* dst;
    if (i8 < nu) {
        src = user + i8; dst = ub + i8;
    } else {
        int j = i8 - nu;
        if (j >= ni) return;
        src = item + j; dst = ib + j;
    }
    float4 a = ((const float4*)src)[0];
    float4 c = ((const float4*)src)[1];
    s16x8 r;
    r[0] = f2bf(a.x); r[1] = f2bf(a.y); r[2] = f2bf(a.z); r[3] = f2bf(a.w);
    r[4] = f2bf(c.x); r[5] = f2bf(c.y); r[6] = f2bf(c.z); r[7] = f2bf(c.w);
    *(s16x8*)dst = r;
}

__device__ __forceinline__ bf16x8 pack8(float4 a, float4 b) {
    bf16x8 r;   // native casts -> v_cvt_pk_bf16_f32 (RNE, same numerics)
    r[0] = (__bf16)a.x; r[1] = (__bf16)a.y; r[2] = (__bf16)a.z; r[3] = (__bf16)a.w;
    r[4] = (__bf16)b.x; r[5] = (__bf16)b.y; r[6] = (__bf16)b.z; r[7] = (__bf16)b.w;
    return r;
}

template<int TAB>
__global__ __launch_bounds__(256, 6) void concat_agg_kernel(
        const float* __restrict__ review,
        const float* __restrict__ user,
        const float* __restrict__ item,
        const short* __restrict__ ub,    // bf16 user table (TAB=1)
        const short* __restrict__ ib,    // bf16 item table (TAB=1)
        const int* __restrict__ uadj,
        const int* __restrict__ iadj,
        const short* __restrict__ WT,    // bf16 bits, [64][192] packed
        float* __restrict__ out,
        int n_reviews) {
    __shared__ short ldsW[DIMS * LDST];   // 26624 B (only LDS in the kernel)

    const int t    = threadIdx.x;
    const int lane = t & 63;
    const int wv   = t >> 6;          // 0..3
    const int m    = lane & 15;
    const int q    = lane >> 4;       // 0..3
    const int r0   = blockIdx.x * MTILE;

    int row = r0 + wv * 16 + m;       // per-lane A-fragment row
    if (row >= n_reviews) row = n_reviews - 1;

    // adjacency first: latency hides under WT staging + barrier
    const int u  = uadj[row];
    const int it = iadj[row];

    // --- stage WT once per block (1536 chunks of 8 bf16; 6 per thread) ---
    #pragma unroll
    for (int i = 0; i < 6; ++i) {
        int c = t + i * 256;
        int n = c / 24;
        int k = (c - n * 24) * 8;
        *(s16x8*)&ldsW[n * LDST + k] = *(const s16x8*)(WT + c * 8);
    }

    __syncthreads();   // ldsW ready; X loads issue AFTER this (no vmcnt(0) drain)

    // --- X loads in fragment layout, consumption order: review, user, item ---
    const float* rv = review + (size_t)row * DIMS + q * 8;
    float4 x0 = ((const float4*)rv)[0];
    float4 x1 = ((const float4*)rv)[1];
    float4 x2 = ((const float4*)(rv + 32))[0];
    float4 x3 = ((const float4*)(rv + 32))[1];

    bf16x8 a2, a3, a4, a5;
    if (TAB) {
        const short* uvp = ub + (size_t)u  * DIMS + q * 8;
        const short* ivp = ib + (size_t)it * DIMS + q * 8;
        a2 = __builtin_bit_cast(bf16x8, *(const s16x8*)uvp);
        a3 = __builtin_bit_cast(bf16x8, *(const s16x8*)(uvp + 32));
        a4 = __builtin_bit_cast(bf16x8, *(const s16x8*)ivp);
        a5 = __builtin_bit_cast(bf16x8, *(const s16x8*)(ivp + 32));
    } else {
        const float* uv = user + (size_t)u  * DIMS + q * 8;
        const float* iv = item + (size_t)it * DIMS + q * 8;
        float4 u0 = ((const float4*)uv)[0],        u1 = ((const float4*)uv)[1];
        float4 u2 = ((const float4*)(uv + 32))[0], u3 = ((const float4*)(uv + 32))[1];
        float4 i0 = ((const float4*)iv)[0],        i1 = ((const float4*)iv)[1];
        float4 i2 = ((const float4*)(iv + 32))[0], i3 = ((const float4*)(iv + 32))[1];
        a2 = pack8(u0, u1); a3 = pack8(u2, u3);
        a4 = pack8(i0, i1); a5 = pack8(i2, i3);
    }
    bf16x8 a0 = pack8(x0, x1);
    bf16x8 a1 = pack8(x2, x3);

    const short* wb0 = &ldsW[m * LDST + q * 8];

    f32x4 acc0 = {0.f,0.f,0.f,0.f}, acc1 = {0.f,0.f,0.f,0.f};
    f32x4 acc2 = {0.f,0.f,0.f,0.f}, acc3 = {0.f,0.f,0.f,0.f};

    #define KSTEP(A, KS) do { \
        bf16x8 b0 = __builtin_bit_cast(bf16x8, *(const s16x8*)(wb0 + 0 * 16 * LDST + (KS) * 32)); \
        bf16x8 b1 = __builtin_bit_cast(bf16x8, *(const s16x8*)(wb0 + 1 * 16 * LDST + (KS) * 32)); \
        bf16x8 b2 = __builtin_bit_cast(bf16x8, *(const s16x8*)(wb0 + 2 * 16 * LDST + (KS) * 32)); \
        bf16x8 b3 = __builtin_bit_cast(bf16x8, *(const s16x8*)(wb0 + 3 * 16 * LDST + (KS) * 32)); \
        acc0 = __builtin_amdgcn_mfma_f32_16x16x32_bf16((A), b0, acc0, 0, 0, 0); \
        acc1 = __builtin_amdgcn_mfma_f32_16x16x32_bf16((A), b1, acc1, 0, 0, 0); \
        acc2 = __builtin_amdgcn_mfma_f32_16x16x32_bf16((A), b2, acc2, 0, 0, 0); \
        acc3 = __builtin_amdgcn_mfma_f32_16x16x32_bf16((A), b3, acc3, 0, 0, 0); \
    } while (0)

    KSTEP(a0, 0);
    KSTEP(a1, 1);
    KSTEP(a2, 2);
    KSTEP(a3, 3);
    KSTEP(a4, 4);
    KSTEP(a5, 5);
    #undef KSTEP

    // --- epilogue: C/D layout col = lane&15, row = q*4 + reg ---
    #pragma unroll
    for (int v = 0; v < 4; ++v) {
        const int rr = r0 + wv * 16 + q * 4 + v;
        if (rr < n_reviews) {
            float* orow = out + (size_t)rr * DIMS + m;
            orow[ 0] = fmaxf(acc0[v], 0.0f);
            orow[16] = fmaxf(acc1[v], 0.0f);
            orow[32] = fmaxf(acc2[v], 0.0f);
            orow[48] = fmaxf(acc3[v], 0.0f);
        }
    }
}

extern "C" void kernel_launch(void* const* d_in, const int* in_sizes, int n_in,
                              void* d_out, int out_size, void* d_ws, size_t ws_size,
                              hipStream_t stream) {
    (void)n_in; (void)out_size;
    const float* review = (const float*)d_in[0];
    const float* user   = (const float*)d_in[1];
    const float* item   = (const float*)d_in[2];
    const float* W      = (const float*)d_in[3];
    const int* uadj     = (const int*)d_in[4];
    const int* iadj     = (const int*)d_in[5];
    const int* perm_u   = (const int*)d_in[6];
    const int* perm_i   = (const int*)d_in[7];
    float* out = (float*)d_out;

    const int n_reviews = in_sizes[0] / DIMS;
    const int nu = in_sizes[1];    // user table float count (100000*64)
    const int ni = in_sizes[2];    // item table float count (50000*64)

    short* WT = (short*)d_ws;      // 24576 B at offset 0
    const size_t off_ub = 32768;
    const size_t need = off_ub + (size_t)(nu + ni) * sizeof(short);

    const int grid = (n_reviews + MTILE - 1) / MTILE;

    if (ws_size >= need) {
        short* UB = (short*)((char*)d_ws + off_ub);
        short* IB = UB + nu;
        const int tabBlocks = (nu + ni + 2047) / 2048;   // 8 elems/thread
        prep_all<<<tabBlocks + 6, 256, 0, stream>>>(W, perm_u, perm_i, user, item,
                                                    WT, UB, IB, nu, ni, tabBlocks);
        concat_agg_kernel<1><<<grid, 256, 0, stream>>>(review, user, item, UB, IB,
                                                       uadj, iadj, WT, out, n_reviews);
    } else {
        prep_WT<<<6, 256, 0, stream>>>(W, perm_u, perm_i, WT);
        concat_agg_kernel<0><<<grid, 256, 0, stream>>>(review, user, item, nullptr, nullptr,
                                                       uadj, iadj, WT, out, n_reviews);
    }
}

// Round 5
// 478.037 us; speedup vs baseline: 1.1496x; 1.0110x over previous
//
#include <hip/hip_runtime.h>
#include <hip/hip_bf16.h>

// out[r, n] = relu( sum_k concat[r,k] * W[k,n] ),
// concat = [review_row | user_row[perm_u] | item_row[perm_i]]
// WT has W's rows pre-permuted so gathers are contiguous rows.
//
// v6 (on top of v5):
//  - 512-thread blocks (8 waves) share ONE ldsW copy, MTILE=128.
//    LDS/wave halves -> 4 blocks/CU x 8 waves = 32 waves/CU (100% wave cap,
//    was 62%). More waves = more 64B gather lines in flight = higher BW.
//    (Arithmetic: 6.3 TB/s needs ~9.2KB in flight/CU; at 20 waves we were
//    marginal -> 3.8 TB/s. 32 waves pushes past it.)
//  - __launch_bounds__(512,8): VGPR cap 64. Loads stay AFTER the barrier
//    (v3 lesson: pre-barrier loads + vmcnt(0) drain let the allocator
//    serialize them).
//  - everything else unchanged: bf16 tables gathered directly as MFMA
//    A-fragments, merged prep kernel, native cvt_pk bf16 packing.

#define DIMS 64
#define K3 192
#define MTILE 128      // rows per block (16 per wave, 8 waves)
#define NTHREADS 512
#define LDST 208       // LDS row stride in bf16 units (192 + 16 pad)

typedef float f32x4 __attribute__((ext_vector_type(4)));
typedef short s16x8 __attribute__((ext_vector_type(8)));
typedef __bf16 bf16x8 __attribute__((ext_vector_type(8)));

__device__ __forceinline__ short f2bf(float f) {
    union { float f; unsigned int u; } v; v.f = f;
    unsigned int u = v.u;
    u += 0x7fffu + ((u >> 16) & 1u);   // round-to-nearest-even
    return (short)(u >> 16);
}

__device__ __forceinline__ void wt_part(const float* __restrict__ W,
                                        const int* __restrict__ perm_u,
                                        const int* __restrict__ perm_i,
                                        short* __restrict__ WT,
                                        int wtb, int t) {
    #pragma unroll
    for (int i = 0; i < 8; ++i) {
        int e = t + (wtb * 8 + i) * 256;  // 0..12287 over 6 blocks
        int k = e >> 6;                   // 0..191
        int n = e & 63;
        float w = W[e];                   // coalesced
        int dk;
        if (k < 64)       dk = k;
        else if (k < 128) dk = 64 + perm_u[k - 64];
        else              dk = 128 + perm_i[k - 128];
        WT[n * K3 + dk] = f2bf(w);
    }
}

// Fallback (small workspace): WT only, 6 blocks of 256.
__global__ void prep_WT(const float* __restrict__ W,
                        const int* __restrict__ perm_u,
                        const int* __restrict__ perm_i,
                        short* __restrict__ WT) {
    wt_part(W, perm_u, perm_i, WT, blockIdx.x, threadIdx.x);
}

// Merged prep: blocks [0, tabBlocks) convert user+item tables f32->bf16;
// blocks [tabBlocks, tabBlocks+6) build WT. One launch, fully parallel.
__global__ void prep_all(const float* __restrict__ W,
                         const int* __restrict__ perm_u,
                         const int* __restrict__ perm_i,
                         const float* __restrict__ user,
                         const float* __restrict__ item,
                         short* __restrict__ WT,
                         short* __restrict__ ub, short* __restrict__ ib,
                         int nu, int ni, int tabBlocks) {
    const int t = threadIdx.x;
    const int b = blockIdx.x;
    if (b >= tabBlocks) {
        wt_part(W, perm_u, perm_i, WT, b - tabBlocks, t);
        return;
    }
    int i8 = (b * 256 + t) * 8;
    const float* src;
    short* dst;
    if (i8 < nu) {
        src = user + i8; dst = ub + i8;
    } else {
        int j = i8 - nu;
        if (j >= ni) return;
        src = item + j; dst = ib + j;
    }
    float4 a = ((const float4*)src)[0];
    float4 c = ((const float4*)src)[1];
    s16x8 r;
    r[0] = f2bf(a.x); r[1] = f2bf(a.y); r[2] = f2bf(a.z); r[3] = f2bf(a.w);
    r[4] = f2bf(c.x); r[5] = f2bf(c.y); r[6] = f2bf(c.z); r[7] = f2bf(c.w);
    *(s16x8*)dst = r;
}

__device__ __forceinline__ bf16x8 pack8(float4 a, float4 b) {
    bf16x8 r;   // native casts -> v_cvt_pk_bf16_f32 (RNE, same numerics)
    r[0] = (__bf16)a.x; r[1] = (__bf16)a.y; r[2] = (__bf16)a.z; r[3] = (__bf16)a.w;
    r[4] = (__bf16)b.x; r[5] = (__bf16)b.y; r[6] = (__bf16)b.z; r[7] = (__bf16)b.w;
    return r;
}

template<int TAB>
__global__ __launch_bounds__(NTHREADS, 8) void concat_agg_kernel(
        const float* __restrict__ review,
        const float* __restrict__ user,
        const float* __restrict__ item,
        const short* __restrict__ ub,    // bf16 user table (TAB=1)
        const short* __restrict__ ib,    // bf16 item table (TAB=1)
        const int* __restrict__ uadj,
        const int* __restrict__ iadj,
        const short* __restrict__ WT,    // bf16 bits, [64][192] packed
        float* __restrict__ out,
        int n_reviews) {
    __shared__ short ldsW[DIMS * LDST];   // 26624 B, shared by all 8 waves

    const int t    = threadIdx.x;
    const int lane = t & 63;
    const int wv   = t >> 6;          // 0..7
    const int m    = lane & 15;
    const int q    = lane >> 4;       // 0..3
    const int r0   = blockIdx.x * MTILE;

    int row = r0 + wv * 16 + m;       // per-lane A-fragment row
    if (row >= n_reviews) row = n_reviews - 1;

    // adjacency first: latency hides under WT staging + barrier
    const int u  = uadj[row];
    const int it = iadj[row];

    // --- stage WT once per block (1536 chunks of 8 bf16; 3 per thread) ---
    #pragma unroll
    for (int i = 0; i < 3; ++i) {
        int c = t + i * NTHREADS;
        int n = c / 24;
        int k = (c - n * 24) * 8;
        *(s16x8*)&ldsW[n * LDST + k] = *(const s16x8*)(WT + c * 8);
    }

    __syncthreads();   // ldsW ready; X loads issue AFTER this (no vmcnt(0) drain)

    // --- X loads in fragment layout, consumption order: review, user, item ---
    const float* rv = review + (size_t)row * DIMS + q * 8;
    float4 x0 = ((const float4*)rv)[0];
    float4 x1 = ((const float4*)rv)[1];
    float4 x2 = ((const float4*)(rv + 32))[0];
    float4 x3 = ((const float4*)(rv + 32))[1];

    bf16x8 a2, a3, a4, a5;
    if (TAB) {
        const short* uvp = ub + (size_t)u  * DIMS + q * 8;
        const short* ivp = ib + (size_t)it * DIMS + q * 8;
        a2 = __builtin_bit_cast(bf16x8, *(const s16x8*)uvp);
        a3 = __builtin_bit_cast(bf16x8, *(const s16x8*)(uvp + 32));
        a4 = __builtin_bit_cast(bf16x8, *(const s16x8*)ivp);
        a5 = __builtin_bit_cast(bf16x8, *(const s16x8*)(ivp + 32));
    } else {
        const float* uv = user + (size_t)u  * DIMS + q * 8;
        const float* iv = item + (size_t)it * DIMS + q * 8;
        float4 u0 = ((const float4*)uv)[0],        u1 = ((const float4*)uv)[1];
        float4 u2 = ((const float4*)(uv + 32))[0], u3 = ((const float4*)(uv + 32))[1];
        float4 i0 = ((const float4*)iv)[0],        i1 = ((const float4*)iv)[1];
        float4 i2 = ((const float4*)(iv + 32))[0], i3 = ((const float4*)(iv + 32))[1];
        a2 = pack8(u0, u1); a3 = pack8(u2, u3);
        a4 = pack8(i0, i1); a5 = pack8(i2, i3);
    }
    bf16x8 a0 = pack8(x0, x1);
    bf16x8 a1 = pack8(x2, x3);

    const short* wb0 = &ldsW[m * LDST + q * 8];

    f32x4 acc0 = {0.f,0.f,0.f,0.f}, acc1 = {0.f,0.f,0.f,0.f};
    f32x4 acc2 = {0.f,0.f,0.f,0.f}, acc3 = {0.f,0.f,0.f,0.f};

    #define KSTEP(A, KS) do { \
        bf16x8 b0 = __builtin_bit_cast(bf16x8, *(const s16x8*)(wb0 + 0 * 16 * LDST + (KS) * 32)); \
        bf16x8 b1 = __builtin_bit_cast(bf16x8, *(const s16x8*)(wb0 + 1 * 16 * LDST + (KS) * 32)); \
        bf16x8 b2 = __builtin_bit_cast(bf16x8, *(const s16x8*)(wb0 + 2 * 16 * LDST + (KS) * 32)); \
        bf16x8 b3 = __builtin_bit_cast(bf16x8, *(const s16x8*)(wb0 + 3 * 16 * LDST + (KS) * 32)); \
        acc0 = __builtin_amdgcn_mfma_f32_16x16x32_bf16((A), b0, acc0, 0, 0, 0); \
        acc1 = __builtin_amdgcn_mfma_f32_16x16x32_bf16((A), b1, acc1, 0, 0, 0); \
        acc2 = __builtin_amdgcn_mfma_f32_16x16x32_bf16((A), b2, acc2, 0, 0, 0); \
        acc3 = __builtin_amdgcn_mfma_f32_16x16x32_bf16((A), b3, acc3, 0, 0, 0); \
    } while (0)

    KSTEP(a0, 0);
    KSTEP(a1, 1);
    KSTEP(a2, 2);
    KSTEP(a3, 3);
    KSTEP(a4, 4);
    KSTEP(a5, 5);
    #undef KSTEP

    // --- epilogue: C/D layout col = lane&15, row = q*4 + reg ---
    #pragma unroll
    for (int v = 0; v < 4; ++v) {
        const int rr = r0 + wv * 16 + q * 4 + v;
        if (rr < n_reviews) {
            float* orow = out + (size_t)rr * DIMS + m;
            orow[ 0] = fmaxf(acc0[v], 0.0f);
            orow[16] = fmaxf(acc1[v], 0.0f);
            orow[32] = fmaxf(acc2[v], 0.0f);
            orow[48] = fmaxf(acc3[v], 0.0f);
        }
    }
}

extern "C" void kernel_launch(void* const* d_in, const int* in_sizes, int n_in,
                              void* d_out, int out_size, void* d_ws, size_t ws_size,
                              hipStream_t stream) {
    (void)n_in; (void)out_size;
    const float* review = (const float*)d_in[0];
    const float* user   = (const float*)d_in[1];
    const float* item   = (const float*)d_in[2];
    const float* W      = (const float*)d_in[3];
    const int* uadj     = (const int*)d_in[4];
    const int* iadj     = (const int*)d_in[5];
    const int* perm_u   = (const int*)d_in[6];
    const int* perm_i   = (const int*)d_in[7];
    float* out = (float*)d_out;

    const int n_reviews = in_sizes[0] / DIMS;
    const int nu = in_sizes[1];    // user table float count (100000*64)
    const int ni = in_sizes[2];    // item table float count (50000*64)

    short* WT = (short*)d_ws;      // 24576 B at offset 0
    const size_t off_ub = 32768;
    const size_t need = off_ub + (size_t)(nu + ni) * sizeof(short);

    const int grid = (n_reviews + MTILE - 1) / MTILE;

    if (ws_size >= need) {
        short* UB = (short*)((char*)d_ws + off_ub);
        short* IB = UB + nu;
        const int tabBlocks = (nu + ni + 2047) / 2048;   // 8 elems/thread
        prep_all<<<tabBlocks + 6, 256, 0, stream>>>(W, perm_u, perm_i, user, item,
                                                    WT, UB, IB, nu, ni, tabBlocks);
        concat_agg_kernel<1><<<grid, NTHREADS, 0, stream>>>(review, user, item, UB, IB,
                                                            uadj, iadj, WT, out, n_reviews);
    } else {
        prep_WT<<<6, 256, 0, stream>>>(W, perm_u, perm_i, WT);
        concat_agg_kernel<0><<<grid, NTHREADS, 0, stream>>>(review, user, item, nullptr, nullptr,
                                                            uadj, iadj, WT, out, n_reviews);
    }
}

// Round 6
// 469.107 us; speedup vs baseline: 1.1715x; 1.0190x over previous
//
#include <hip/hip_runtime.h>
#include <hip/hip_bf16.h>

// out[r, n] = relu( sum_k concat[r,k] * W[k,n] ),
// concat = [review_row | user_row[perm_u] | item_row[perm_i]]
// WT has W's rows pre-permuted so gathers are contiguous rows.
//
// v7 (on top of v6):
//  - VMEM-instruction diet. BW is invariant to waves x MLP (v1..v6 all pin
//    at ~3.7 TB/s with neither pipe busy) -> hypothesis: TA/address-issue
//    bound. The epilogue was 16 scalar 4B stores/thread (55% of the 29
//    global VMEM instrs). Now: after the MFMAs, ldsW is dead; one extra
//    __syncthreads() and each wave reuses a private 4.3KB LDS slice to
//    transpose C, then issues 4 global_store_dwordx4 (1KB contiguous per
//    instruction). 29 -> 17 global VMEM instrs/thread.
//  - LDS bank patterns verified: ds_write 2-way max (stride 68), free.
//  - __launch_bounds__(512,6): 84-VGPR budget so the 12-deep load MLP
//    cannot be register-serialized (v3 lesson). 24 waves/CU.

#define DIMS 64
#define K3 192
#define MTILE 128      // rows per block (16 per wave, 8 waves)
#define NTHREADS 512
#define LDST 208       // LDS row stride in bf16 units (192 + 16 pad)
#define TBS 68         // epilogue transpose-buffer row stride (floats)

typedef float f32x4 __attribute__((ext_vector_type(4)));
typedef short s16x8 __attribute__((ext_vector_type(8)));
typedef __bf16 bf16x8 __attribute__((ext_vector_type(8)));

__device__ __forceinline__ short f2bf(float f) {
    union { float f; unsigned int u; } v; v.f = f;
    unsigned int u = v.u;
    u += 0x7fffu + ((u >> 16) & 1u);   // round-to-nearest-even
    return (short)(u >> 16);
}

__device__ __forceinline__ void wt_part(const float* __restrict__ W,
                                        const int* __restrict__ perm_u,
                                        const int* __restrict__ perm_i,
                                        short* __restrict__ WT,
                                        int wtb, int t) {
    #pragma unroll
    for (int i = 0; i < 8; ++i) {
        int e = t + (wtb * 8 + i) * 256;  // 0..12287 over 6 blocks
        int k = e >> 6;                   // 0..191
        int n = e & 63;
        float w = W[e];                   // coalesced
        int dk;
        if (k < 64)       dk = k;
        else if (k < 128) dk = 64 + perm_u[k - 64];
        else              dk = 128 + perm_i[k - 128];
        WT[n * K3 + dk] = f2bf(w);
    }
}

// Fallback (small workspace): WT only, 6 blocks of 256.
__global__ void prep_WT(const float* __restrict__ W,
                        const int* __restrict__ perm_u,
                        const int* __restrict__ perm_i,
                        short* __restrict__ WT) {
    wt_part(W, perm_u, perm_i, WT, blockIdx.x, threadIdx.x);
}

// Merged prep: blocks [0, tabBlocks) convert user+item tables f32->bf16;
// blocks [tabBlocks, tabBlocks+6) build WT. One launch, fully parallel.
__global__ void prep_all(const float* __restrict__ W,
                         const int* __restrict__ perm_u,
                         const int* __restrict__ perm_i,
                         const float* __restrict__ user,
                         const float* __restrict__ item,
                         short* __restrict__ WT,
                         short* __restrict__ ub, short* __restrict__ ib,
                         int nu, int ni, int tabBlocks) {
    const int t = threadIdx.x;
    const int b = blockIdx.x;
    if (b >= tabBlocks) {
        wt_part(W, perm_u, perm_i, WT, b - tabBlocks, t);
        return;
    }
    int i8 = (b * 256 + t) * 8;
    const float* src;
    short* dst;
    if (i8 < nu) {
        src = user + i8; dst = ub + i8;
    } else {
        int j = i8 - nu;
        if (j >= ni) return;
        src = item + j; dst = ib + j;
    }
    float4 a = ((const float4*)src)[0];
    float4 c = ((const float4*)src)[1];
    s16x8 r;
    r[0] = f2bf(a.x); r[1] = f2bf(a.y); r[2] = f2bf(a.z); r[3] = f2bf(a.w);
    r[4] = f2bf(c.x); r[5] = f2bf(c.y); r[6] = f2bf(c.z); r[7] = f2bf(c.w);
    *(s16x8*)dst = r;
}

__device__ __forceinline__ bf16x8 pack8(float4 a, float4 b) {
    bf16x8 r;   // native casts -> v_cvt_pk_bf16_f32 (RNE, same numerics)
    r[0] = (__bf16)a.x; r[1] = (__bf16)a.y; r[2] = (__bf16)a.z; r[3] = (__bf16)a.w;
    r[4] = (__bf16)b.x; r[5] = (__bf16)b.y; r[6] = (__bf16)b.z; r[7] = (__bf16)b.w;
    return r;
}

template<int TAB>
__global__ __launch_bounds__(NTHREADS, 6) void concat_agg_kernel(
        const float* __restrict__ review,
        const float* __restrict__ user,
        const float* __restrict__ item,
        const short* __restrict__ ub,    // bf16 user table (TAB=1)
        const short* __restrict__ ib,    // bf16 item table (TAB=1)
        const int* __restrict__ uadj,
        const int* __restrict__ iadj,
        const short* __restrict__ WT,    // bf16 bits, [64][192] packed
        float* __restrict__ out,
        int n_reviews) {
    // Phase 1 (GEMM): first 26624 B hold ldsW.
    // Phase 2 (epilogue, after barrier): 8 waves x 16 rows x TBS floats.
    __shared__ float ldsF[8 * 16 * TBS];          // 34816 B
    short* ldsW = (short*)ldsF;

    const int t    = threadIdx.x;
    const int lane = t & 63;
    const int wv   = t >> 6;          // 0..7
    const int m    = lane & 15;
    const int q    = lane >> 4;       // 0..3
    const int r0   = blockIdx.x * MTILE;

    int row = r0 + wv * 16 + m;       // per-lane A-fragment row
    if (row >= n_reviews) row = n_reviews - 1;

    // adjacency first: latency hides under WT staging + barrier
    const int u  = uadj[row];
    const int it = iadj[row];

    // --- stage WT once per block (1536 chunks of 8 bf16; 3 per thread) ---
    #pragma unroll
    for (int i = 0; i < 3; ++i) {
        int c = t + i * NTHREADS;
        int n = c / 24;
        int k = (c - n * 24) * 8;
        *(s16x8*)&ldsW[n * LDST + k] = *(const s16x8*)(WT + c * 8);
    }

    __syncthreads();   // ldsW ready; X loads issue AFTER this (no vmcnt(0) drain)

    // --- X loads in fragment layout, consumption order: review, user, item ---
    const float* rv = review + (size_t)row * DIMS + q * 8;
    float4 x0 = ((const float4*)rv)[0];
    float4 x1 = ((const float4*)rv)[1];
    float4 x2 = ((const float4*)(rv + 32))[0];
    float4 x3 = ((const float4*)(rv + 32))[1];

    bf16x8 a2, a3, a4, a5;
    if (TAB) {
        const short* uvp = ub + (size_t)u  * DIMS + q * 8;
        const short* ivp = ib + (size_t)it * DIMS + q * 8;
        a2 = __builtin_bit_cast(bf16x8, *(const s16x8*)uvp);
        a3 = __builtin_bit_cast(bf16x8, *(const s16x8*)(uvp + 32));
        a4 = __builtin_bit_cast(bf16x8, *(const s16x8*)ivp);
        a5 = __builtin_bit_cast(bf16x8, *(const s16x8*)(ivp + 32));
    } else {
        const float* uv = user + (size_t)u  * DIMS + q * 8;
        const float* iv = item + (size_t)it * DIMS + q * 8;
        float4 u0 = ((const float4*)uv)[0],        u1 = ((const float4*)uv)[1];
        float4 u2 = ((const float4*)(uv + 32))[0], u3 = ((const float4*)(uv + 32))[1];
        float4 i0 = ((const float4*)iv)[0],        i1 = ((const float4*)iv)[1];
        float4 i2 = ((const float4*)(iv + 32))[0], i3 = ((const float4*)(iv + 32))[1];
        a2 = pack8(u0, u1); a3 = pack8(u2, u3);
        a4 = pack8(i0, i1); a5 = pack8(i2, i3);
    }
    bf16x8 a0 = pack8(x0, x1);
    bf16x8 a1 = pack8(x2, x3);

    const short* wb0 = &ldsW[m * LDST + q * 8];

    f32x4 acc0 = {0.f,0.f,0.f,0.f}, acc1 = {0.f,0.f,0.f,0.f};
    f32x4 acc2 = {0.f,0.f,0.f,0.f}, acc3 = {0.f,0.f,0.f,0.f};

    #define KSTEP(A, KS) do { \
        bf16x8 b0 = __builtin_bit_cast(bf16x8, *(const s16x8*)(wb0 + 0 * 16 * LDST + (KS) * 32)); \
        bf16x8 b1 = __builtin_bit_cast(bf16x8, *(const s16x8*)(wb0 + 1 * 16 * LDST + (KS) * 32)); \
        bf16x8 b2 = __builtin_bit_cast(bf16x8, *(const s16x8*)(wb0 + 2 * 16 * LDST + (KS) * 32)); \
        bf16x8 b3 = __builtin_bit_cast(bf16x8, *(const s16x8*)(wb0 + 3 * 16 * LDST + (KS) * 32)); \
        acc0 = __builtin_amdgcn_mfma_f32_16x16x32_bf16((A), b0, acc0, 0, 0, 0); \
        acc1 = __builtin_amdgcn_mfma_f32_16x16x32_bf16((A), b1, acc1, 0, 0, 0); \
        acc2 = __builtin_amdgcn_mfma_f32_16x16x32_bf16((A), b2, acc2, 0, 0, 0); \
        acc3 = __builtin_amdgcn_mfma_f32_16x16x32_bf16((A), b3, acc3, 0, 0, 0); \
    } while (0)

    KSTEP(a0, 0);
    KSTEP(a1, 1);
    KSTEP(a2, 2);
    KSTEP(a3, 3);
    KSTEP(a4, 4);
    KSTEP(a5, 5);
    #undef KSTEP

    // --- epilogue: transpose through LDS, store dwordx4 ---
    __syncthreads();   // all waves done reading ldsW; safe to reuse

    float* tb = ldsF + wv * (16 * TBS);   // private per-wave slice
    // ds_write pattern (fixed v): banks = (16q + m) % 32 -> exactly 2-way (free)
    #pragma unroll
    for (int v = 0; v < 4; ++v) {
        const int rr = q * 4 + v;
        tb[rr * TBS + m +  0] = fmaxf(acc0[v], 0.0f);
        tb[rr * TBS + m + 16] = fmaxf(acc1[v], 0.0f);
        tb[rr * TBS + m + 32] = fmaxf(acc2[v], 0.0f);
        tb[rr * TBS + m + 48] = fmaxf(acc3[v], 0.0f);
    }
    // store k: rows 4k..4k+3 of this wave's 16-row tile, 1KB contiguous/instr
    const int scol = m * 4;
    #pragma unroll
    for (int k = 0; k < 4; ++k) {
        const int lr = 4 * k + q;
        f32x4 o = *(const f32x4*)&tb[lr * TBS + scol];
        const int grow = r0 + wv * 16 + lr;
        if (grow < n_reviews)
            *(f32x4*)(out + (size_t)grow * DIMS + scol) = o;
    }
}

extern "C" void kernel_launch(void* const* d_in, const int* in_sizes, int n_in,
                              void* d_out, int out_size, void* d_ws, size_t ws_size,
                              hipStream_t stream) {
    (void)n_in; (void)out_size;
    const float* review = (const float*)d_in[0];
    const float* user   = (const float*)d_in[1];
    const float* item   = (const float*)d_in[2];
    const float* W      = (const float*)d_in[3];
    const int* uadj     = (const int*)d_in[4];
    const int* iadj     = (const int*)d_in[5];
    const int* perm_u   = (const int*)d_in[6];
    const int* perm_i   = (const int*)d_in[7];
    float* out = (float*)d_out;

    const int n_reviews = in_sizes[0] / DIMS;
    const int nu = in_sizes[1];    // user table float count (100000*64)
    const int ni = in_sizes[2];    // item table float count (50000*64)

    short* WT = (short*)d_ws;      // 24576 B at offset 0
    const size_t off_ub = 32768;
    const size_t need = off_ub + (size_t)(nu + ni) * sizeof(short);

    const int grid = (n_reviews + MTILE - 1) / MTILE;

    if (ws_size >= need) {
        short* UB = (short*)((char*)d_ws + off_ub);
        short* IB = UB + nu;
        const int tabBlocks = (nu + ni + 2047) / 2048;   // 8 elems/thread
        prep_all<<<tabBlocks + 6, 256, 0, stream>>>(W, perm_u, perm_i, user, item,
                                                    WT, UB, IB, nu, ni, tabBlocks);
        concat_agg_kernel<1><<<grid, NTHREADS, 0, stream>>>(review, user, item, UB, IB,
                                                            uadj, iadj, WT, out, n_reviews);
    } else {
        prep_WT<<<6, 256, 0, stream>>>(W, perm_u, perm_i, WT);
        concat_agg_kernel<0><<<grid, NTHREADS, 0, stream>>>(review, user, item, nullptr, nullptr,
                                                            uadj, iadj, WT, out, n_reviews);
    }
}